// Round 10
// baseline (347.474 us; speedup 1.0000x reference)
//
#include <hip/hip_runtime.h>
#include <hip/hip_fp16.h>

// ---------------------------------------------------------------------------
// GIN (2 GINConv layers + linear head) on MI355X.
// Round 25 (= R24 resubmit after broker timeout): (a) prep and scatter are
// independent -> merged into ONE launch (blocks [0,NB_S) scatter, rest prep);
// gcur switched to 0-based counts with hipMemsetAsync init so no cross-block
// init ordering is needed. Critical path gains ~min(prep,scatter). (b) MLP
// per-wave LDS halved: GEMM-2/3 run per-m-tile sequentially (epilogue(mt) ->
// immediate read-back(mt)), so the wave scratch is ONE T-region (8.4KB)
// instead of two -> 33.8KB/block -> 3 blocks/CU (launch_bounds(256,3)),
// +50% waves to hide latency. aggs unchanged: random gather pinned at
// 3.8 TB/s (fabric/L3 throughput, confirmed across R16/R17/R21/R22/R23).
// ---------------------------------------------------------------------------

typedef __attribute__((ext_vector_type(8))) short short8;
typedef __attribute__((ext_vector_type(8))) _Float16 half8;
typedef __attribute__((ext_vector_type(4))) float f32x4;
union F8 { unsigned u[4]; uint4 u4; short8 s; half8 h; };

// ---------------- CSR build (bucket-binned; fused build) ----------------

constexpr int BUCKET_SHIFT = 9;
constexpr int BUCKET_NODES = 1 << BUCKET_SHIFT;
constexpr int CAP = 10240;
constexpr int EPB = 2048;
constexpr int NBUCK_MAX = 256;

// merged prep + scatter: blocks [0,nbs) bin edges into gpk (gcur 0-based,
// memset beforehand); blocks [nbs, nbs+12500) convert weights + x -> fp16.
__global__ __launch_bounds__(256) void prep_scatter_kernel(const int* __restrict__ ei, int E,
                                                           int* __restrict__ gcur,
                                                           int* __restrict__ gpk,
                                                           int nbuck, int nbs,
                                                           const float* __restrict__ W1a,
                                                           const float* __restrict__ W1b,
                                                           const float* __restrict__ W2a,
                                                           const float* __restrict__ W2b,
                                                           const float* __restrict__ Wlin,
                                                           short* __restrict__ hi,
                                                           const float* __restrict__ x,
                                                           __half2* __restrict__ x16, int n2,
                                                           int npb) {
    __shared__ int spk[EPB];
    __shared__ unsigned char sbuck[EPB];
    __shared__ int lcnt[NBUCK_MAX];
    __shared__ int lbase[NBUCK_MAX];
    __shared__ int lcur[NBUCK_MAX];
    __shared__ int gbase[NBUCK_MAX];
    __shared__ int stmp[256];

    const int t = threadIdx.x;

    if (blockIdx.x >= nbs) {
        // ---- prep branch ----
        int pb = blockIdx.x - nbs;
        int i = pb * 256 + t;
        if (i < 65536) {
            const float* W;
            int base, K, N;
            if (i < 8192)       { W = W1a;  base = 0;     K = 64;  N = 128; }
            else if (i < 24576) { W = W1b;  base = 8192;  K = 128; N = 128; }
            else if (i < 40960) { W = W2a;  base = 24576; K = 128; N = 128; }
            else if (i < 57344) { W = W2b;  base = 40960; K = 128; N = 128; }
            else                { W = Wlin; base = 57344; K = 128; N = 64;  }
            int rel = i - base;
            int NT = N >> 4;
            int j  = rel & 7;
            int l  = (rel >> 3) & 63;
            int tc = rel >> 9;            // c*NT + nt
            int nt = tc % NT;
            int c  = tc / NT;
            int n  = nt * 16 + (l & 15);
            int k  = c * 32 + ((l >> 4) << 3) + j;
            float v = W[k * N + n];
            hi[i] = (short)__half_as_ushort(__float2half_rn(v));
        }
        for (int k = i; k < n2; k += npb * 256) {
            float2 v = reinterpret_cast<const float2*>(x)[k];
            x16[k] = __floats2half2_rn(v.x, v.y);
        }
        return;
    }

    // ---- scatter branch ----
    const int e0 = blockIdx.x * EPB;
    const int ecnt = min(EPB, E - e0);

    for (int i = t; i < NBUCK_MAX; i += 256) lcnt[i] = 0;
    __syncthreads();

    for (int i = t; i < ecnt; i += 256) {
        int d = ei[E + e0 + i];
        atomicAdd(&lcnt[d >> BUCKET_SHIFT], 1);
    }
    __syncthreads();

    int v = lcnt[t];
    stmp[t] = v;
    __syncthreads();
    #pragma unroll
    for (int off = 1; off < 256; off <<= 1) {
        int add = (t >= off) ? stmp[t - off] : 0;
        __syncthreads();
        stmp[t] += add;
        __syncthreads();
    }
    lbase[t] = stmp[t] - v;
    lcur[t] = stmp[t] - v;
    __syncthreads();

    for (int i = t; i < ecnt; i += 256) {
        int s = ei[e0 + i];
        int d = ei[E + e0 + i];
        int b = d >> BUCKET_SHIFT;
        int p = atomicAdd(&lcur[b], 1);
        spk[p] = ((d & (BUCKET_NODES - 1)) << 17) | s;
        sbuck[p] = (unsigned char)b;
    }
    __syncthreads();

    if (t < nbuck) {
        int c = lcnt[t];
        gbase[t] = (c > 0) ? atomicAdd(&gcur[t], c) : 0;   // 0-based position
    }
    __syncthreads();

    for (int i = t; i < ecnt; i += 256) {
        int b = sbuck[i];
        int gp = gbase[b] + (i - lbase[b]);                 // within-bucket pos
        if (gp < CAP) gpk[(size_t)b * CAP + gp] = spk[i];
    }
}

// fused: per-block bucket-base scan + hist + per-bucket node scan +
// row_start write + fill. One 1024-thread block per bucket. gcur is 0-based.
__global__ __launch_bounds__(1024) void bucket_build_kernel(const int* __restrict__ gpk,
                                                            const int* __restrict__ gcur,
                                                            int* __restrict__ row_start,
                                                            int* __restrict__ edge_src,
                                                            int N, int E, int nbuck) {
    __shared__ int h[BUCKET_NODES];
    __shared__ int s[BUCKET_NODES];
    __shared__ int sb[NBUCK_MAX];
    __shared__ int bbase_sh;
    const int t = threadIdx.x;
    const int b = blockIdx.x;
    const int base = b << BUCKET_SHIFT;

    if (t < NBUCK_MAX) {
        int c = 0;
        if (t < nbuck) c = min(gcur[t], CAP);
        sb[t] = c;
    }
    for (int i = t; i < BUCKET_NODES; i += 1024) h[i] = 0;
    __syncthreads();
    #pragma unroll
    for (int off = 1; off < NBUCK_MAX; off <<= 1) {
        int add = (t >= off && t < NBUCK_MAX) ? sb[t - off] : 0;
        __syncthreads();
        if (t < NBUCK_MAX) sb[t] += add;
        __syncthreads();
    }
    if (t == 0) {
        int cb0 = min(gcur[b], CAP);
        bbase_sh = sb[b] - cb0;   // exclusive base for this bucket
    }

    int cb = min(gcur[b], CAP);
    const int* pp = gpk + (size_t)b * CAP;
    for (int i = t; i < cb; i += 1024) atomicAdd(&h[((unsigned)pp[i]) >> 17], 1);
    __syncthreads();

    int c0 = (t < BUCKET_NODES) ? h[t] : 0;
    if (t < BUCKET_NODES) s[t] = c0;
    __syncthreads();
    #pragma unroll
    for (int off = 1; off < BUCKET_NODES; off <<= 1) {
        int add = (t >= off && t < BUCKET_NODES) ? s[t - off] : 0;
        __syncthreads();
        if (t < BUCKET_NODES) s[t] += add;
        __syncthreads();
    }
    if (t < BUCKET_NODES) {
        int ex = s[t] - c0 + bbase_sh;
        h[t] = ex;                                   // running cursor
        if (base + t < N) row_start[base + t] = ex;
    }
    if (b == 0 && t == 0) row_start[N] = E;
    __syncthreads();

    for (int i = t; i < cb; i += 1024) {
        unsigned pw = (unsigned)pp[i];
        int p = atomicAdd(&h[pw >> 17], 1);
        edge_src[p] = (int)(pw & 0x1FFFFu);
    }
}

// ---------------- aggregation (wide row gathers, R16 form) ----------------

__device__ inline void acc8(float* a, const uint4& v) {
    const __half2* h = reinterpret_cast<const __half2*>(&v);
    #pragma unroll
    for (int j = 0; j < 4; ++j) {
        float2 f = __half22float2(h[j]);
        a[2 * j]     += f.x;
        a[2 * j + 1] += f.y;
    }
}

__device__ inline uint4 pack8(const float* a) {
    uint4 o;
    __half2 h;
    h = __floats2half2_rn(a[0], a[1]); o.x = *reinterpret_cast<unsigned*>(&h);
    h = __floats2half2_rn(a[2], a[3]); o.y = *reinterpret_cast<unsigned*>(&h);
    h = __floats2half2_rn(a[4], a[5]); o.z = *reinterpret_cast<unsigned*>(&h);
    h = __floats2half2_rn(a[6], a[7]); o.w = *reinterpret_cast<unsigned*>(&h);
    return o;
}

// D=128: one node per wave; each 16-lane group fetches a full 256B row as
// dwordx4, so one wave-instruction covers 4 edges (1 KiB in flight).
__global__ __launch_bounds__(256) void agg128_fp16(const __half2* __restrict__ H16,
                                                   const int* __restrict__ row_start,
                                                   const int* __restrict__ edge_src,
                                                   __half2* __restrict__ Z16, int N) {
    int wave = threadIdx.x >> 6, lane = threadIdx.x & 63;
    int node = blockIdx.x * 4 + wave;
    if (node >= N) return;
    const int lg = lane >> 4;      // edge slot 0..3
    const int lo = lane & 15;      // 16B chunk within the row
    const uint4* Hv = reinterpret_cast<const uint4*>(H16);   // 16 uint4 per row
    int beg = row_start[node], end = row_start[node + 1];

    uint4 selfv = Hv[(size_t)node * 16 + lo];   // broadcast across groups

    float a[8];
    #pragma unroll
    for (int j = 0; j < 8; ++j) a[j] = 0.f;
    if (lg == 0) acc8(a, selfv);

    int i = beg;
    for (; i + 16 <= end; i += 16) {
        int s0 = edge_src[i + lg];
        int s1 = edge_src[i + 4 + lg];
        int s2 = edge_src[i + 8 + lg];
        int s3 = edge_src[i + 12 + lg];
        uint4 v0 = Hv[(size_t)s0 * 16 + lo];
        uint4 v1 = Hv[(size_t)s1 * 16 + lo];
        uint4 v2 = Hv[(size_t)s2 * 16 + lo];
        uint4 v3 = Hv[(size_t)s3 * 16 + lo];
        acc8(a, v0); acc8(a, v1); acc8(a, v2); acc8(a, v3);
    }
    if (i + 8 <= end) {
        int s0 = edge_src[i + lg];
        int s1 = edge_src[i + 4 + lg];
        uint4 v0 = Hv[(size_t)s0 * 16 + lo];
        uint4 v1 = Hv[(size_t)s1 * 16 + lo];
        acc8(a, v0); acc8(a, v1);
        i += 8;
    }
    if (i + 4 <= end) {
        int s0 = edge_src[i + lg];
        uint4 v0 = Hv[(size_t)s0 * 16 + lo];
        acc8(a, v0);
        i += 4;
    }
    int rem = end - i;
    if (lg < rem) {
        int s0 = edge_src[i + lg];
        uint4 v0 = Hv[(size_t)s0 * 16 + lo];
        acc8(a, v0);
    }

    // reduce across the 4 lane groups
    #pragma unroll
    for (int j = 0; j < 8; ++j) {
        a[j] += __shfl_xor(a[j], 16);
        a[j] += __shfl_xor(a[j], 32);
    }

    if (lg == 0) {
        reinterpret_cast<uint4*>(Z16)[(size_t)node * 16 + lo] = pack8(a);
    }
}

// D=64: one node per wave; each 8-lane group fetches a full 128B row as
// dwordx4, so one wave-instruction covers 8 edges (1 KiB in flight).
__global__ __launch_bounds__(256) void agg64_fp16(const __half2* __restrict__ H16,
                                                  const int* __restrict__ row_start,
                                                  const int* __restrict__ edge_src,
                                                  __half2* __restrict__ Z16, int N) {
    int wave = threadIdx.x >> 6, lane = threadIdx.x & 63;
    int node = blockIdx.x * 4 + wave;
    if (node >= N) return;
    const int lg = lane >> 3;      // edge slot 0..7
    const int lo = lane & 7;       // 16B chunk within the row
    const uint4* Hv = reinterpret_cast<const uint4*>(H16);   // 8 uint4 per row
    int beg = row_start[node], end = row_start[node + 1];

    uint4 selfv = Hv[(size_t)node * 8 + lo];

    float a[8];
    #pragma unroll
    for (int j = 0; j < 8; ++j) a[j] = 0.f;
    if (lg == 0) acc8(a, selfv);

    int i = beg;
    for (; i + 16 <= end; i += 16) {
        int s0 = edge_src[i + lg];
        int s1 = edge_src[i + 8 + lg];
        uint4 v0 = Hv[(size_t)s0 * 8 + lo];
        uint4 v1 = Hv[(size_t)s1 * 8 + lo];
        acc8(a, v0); acc8(a, v1);
    }
    if (i + 8 <= end) {
        int s0 = edge_src[i + lg];
        uint4 v0 = Hv[(size_t)s0 * 8 + lo];
        acc8(a, v0);
        i += 8;
    }
    int rem = end - i;
    if (lg < rem) {
        int s0 = edge_src[i + lg];
        uint4 v0 = Hv[(size_t)s0 * 8 + lo];
        acc8(a, v0);
    }

    // reduce across the 8 lane groups
    #pragma unroll
    for (int j = 0; j < 8; ++j) {
        a[j] += __shfl_xor(a[j], 8);
        a[j] += __shfl_xor(a[j], 16);
        a[j] += __shfl_xor(a[j], 32);
    }

    if (lg == 0) {
        reinterpret_cast<uint4*>(Z16)[(size_t)node * 8 + lo] = pack8(a);
    }
}

// ---------------- MFMA fused MLP (fp16, per-mt wave scratch) ---------------

// GEMM-1: A-fragment straight from global. f16 fragment mapping:
// row = m0 + T*16 + (lane&15), k = c*32 + (lane>>4)*8 + 0..7
template <int K, int NT>
__device__ inline void compute_directA(const __half2* __restrict__ z, int M, int m0,
                                       const short* __restrict__ WH,
                                       int w, int lane, f32x4 (*acc)[8]) {
    constexpr int KC = K / 32;
    const short8* bhp = reinterpret_cast<const short8*>(WH) + lane;
    const int q = lane >> 4, ln = lane & 15;
    const uint4* zr[2];
    #pragma unroll
    for (int mt = 0; mt < 2; ++mt) {
        int row = m0 + (w * 2 + mt) * 16 + ln;
        if (row >= M) row = M - 1;
        zr[mt] = reinterpret_cast<const uint4*>(z + (size_t)row * (K / 2));
    }
    for (int c = 0; c < KC; ++c) {
        F8 bh[NT];
        #pragma unroll
        for (int nt = 0; nt < NT; ++nt) bh[nt].s = bhp[(c * NT + nt) * 64];
        #pragma unroll
        for (int mt = 0; mt < 2; ++mt) {
            F8 ah;
            ah.u4 = zr[mt][c * 4 + q];
            #pragma unroll
            for (int nt = 0; nt < NT; ++nt) {
                acc[mt][nt] = __builtin_amdgcn_mfma_f32_16x16x32_f16(ah.h, bh[nt].h, acc[mt][nt], 0, 0, 0);
            }
        }
    }
}

// epilogue for ONE m-tile into the wave's private region Pw (4*8*66 dwords).
__device__ inline void epilogue_wave(const f32x4* acc, const float* __restrict__ bias,
                                     unsigned* __restrict__ Pw, int lane) {
    int q = lane >> 4, ln = lane & 15;
    #pragma unroll
    for (int nt = 0; nt < 8; ++nt) {
        int col = nt * 16 + ln;
        float b = bias[col];
        int c = col >> 5, jj = col & 7, q2 = (col >> 3) & 3;
        int pb = (c * 8 + jj) * 66;
        #pragma unroll
        for (int r = 0; r < 4; ++r) {
            float v = fmaxf(acc[nt][r] + b, 0.f);
            Pw[pb + ((q * 4 + r) | (q2 << 4))] =
                (unsigned)__half_as_ushort(__float2half_rn(v));
        }
    }
}

// GEMM-2/3 for ONE m-tile: A from the wave's region (K=128 fixed).
template <int NT>
__device__ inline void compute_fromP(const unsigned* __restrict__ Pw,
                                     const short* __restrict__ WH,
                                     int lane, f32x4* acc) {
    const short8* bhp = reinterpret_cast<const short8*>(WH) + lane;
    for (int c = 0; c < 4; ++c) {
        F8 bh[NT];
        #pragma unroll
        for (int nt = 0; nt < NT; ++nt) bh[nt].s = bhp[(c * NT + nt) * 64];
        const unsigned* Pb = Pw + (c * 8) * 66 + lane;
        unsigned d[8];
        #pragma unroll
        for (int j = 0; j < 8; ++j) d[j] = Pb[j * 66];
        F8 ah;
        #pragma unroll
        for (int j = 0; j < 4; ++j) {
            ah.u[j] = __builtin_amdgcn_perm(d[2 * j + 1], d[2 * j], 0x05040100u);
        }
        #pragma unroll
        for (int nt = 0; nt < NT; ++nt) {
            acc[nt] = __builtin_amdgcn_mfma_f32_16x16x32_f16(ah.h, bh[nt].h, acc[nt], 0, 0, 0);
        }
    }
}

// conv1 MLP: z16[M,64] -> relu(relu(z@Wa+ba)@Wb+bb) = h1 (fp16)
__global__ __launch_bounds__(256, 3) void mfma_mlp_A(const __half2* __restrict__ z16,
                                                     const short* __restrict__ WaH,
                                                     const float* __restrict__ ba,
                                                     const short* __restrict__ WbH,
                                                     const float* __restrict__ bb,
                                                     __half* __restrict__ H16out, int M) {
    __shared__ unsigned P[4 * 4 * 8 * 66];   // 33792 B: 8448 B per wave
    const int t = threadIdx.x;
    const int w = t >> 6, lane = t & 63;
    const int m0 = blockIdx.x * 128;
    const int q = lane >> 4, ln = lane & 15;
    unsigned* Pw = P + w * (4 * 8 * 66);

    f32x4 acc[2][8];
    #pragma unroll
    for (int mt = 0; mt < 2; ++mt)
        #pragma unroll
        for (int i = 0; i < 8; ++i) acc[mt][i] = (f32x4){0.f, 0.f, 0.f, 0.f};
    compute_directA<64, 8>(z16, M, m0, WaH, w, lane, acc);

    #pragma unroll
    for (int mt = 0; mt < 2; ++mt) {
        epilogue_wave(acc[mt], ba, Pw, lane);
        f32x4 a2[8];
        #pragma unroll
        for (int i = 0; i < 8; ++i) a2[i] = (f32x4){0.f, 0.f, 0.f, 0.f};
        compute_fromP<8>(Pw, WbH, lane, a2);
        #pragma unroll
        for (int nt = 0; nt < 8; ++nt) {
            int col = nt * 16 + ln;
            float b = bb[col];
            #pragma unroll
            for (int r = 0; r < 4; ++r) {
                int row = m0 + (w * 2 + mt) * 16 + q * 4 + r;
                if (row < M) {
                    float v = fmaxf(a2[nt][r] + b, 0.f);
                    H16out[(size_t)row * 128 + col] = __float2half_rn(v);
                }
            }
        }
    }
}

// conv2 MLP + head
__global__ __launch_bounds__(256, 3) void mfma_mlp_B(const __half2* __restrict__ z16,
                                                     const short* __restrict__ WaH,
                                                     const float* __restrict__ ba,
                                                     const short* __restrict__ WbH,
                                                     const float* __restrict__ bb,
                                                     const short* __restrict__ WlH,
                                                     const float* __restrict__ bl,
                                                     float* __restrict__ Out, int M) {
    __shared__ unsigned P[4 * 4 * 8 * 66];   // 33792 B: 8448 B per wave
    const int t = threadIdx.x;
    const int w = t >> 6, lane = t & 63;
    const int m0 = blockIdx.x * 128;
    const int q = lane >> 4, ln = lane & 15;
    unsigned* Pw = P + w * (4 * 8 * 66);

    f32x4 acc[2][8];
    #pragma unroll
    for (int mt = 0; mt < 2; ++mt)
        #pragma unroll
        for (int i = 0; i < 8; ++i) acc[mt][i] = (f32x4){0.f, 0.f, 0.f, 0.f};
    compute_directA<128, 8>(z16, M, m0, WaH, w, lane, acc);

    #pragma unroll
    for (int mt = 0; mt < 2; ++mt) {
        epilogue_wave(acc[mt], ba, Pw, lane);
        f32x4 a2[8];
        #pragma unroll
        for (int i = 0; i < 8; ++i) a2[i] = (f32x4){0.f, 0.f, 0.f, 0.f};
        compute_fromP<8>(Pw, WbH, lane, a2);

        epilogue_wave(a2, bb, Pw, lane);
        f32x4 a3[4];
        #pragma unroll
        for (int i = 0; i < 4; ++i) a3[i] = (f32x4){0.f, 0.f, 0.f, 0.f};
        compute_fromP<4>(Pw, WlH, lane, a3);

        #pragma unroll
        for (int nt = 0; nt < 4; ++nt) {
            int col = nt * 16 + ln;
            float b = bl[col];
            #pragma unroll
            for (int r = 0; r < 4; ++r) {
                int row = m0 + (w * 2 + mt) * 16 + q * 4 + r;
                if (row < M) Out[(size_t)row * 64 + col] = a3[nt][r] + b;
            }
        }
    }
}

// ---------------------------------------------------------------------------

extern "C" void kernel_launch(void* const* d_in, const int* in_sizes, int n_in,
                              void* d_out, int out_size, void* d_ws, size_t ws_size,
                              hipStream_t stream) {
    const float* x    = (const float*)d_in[0];
    const int*   ei   = (const int*)d_in[1];
    const float* W1a  = (const float*)d_in[2];
    const float* b1a  = (const float*)d_in[3];
    const float* W1b  = (const float*)d_in[4];
    const float* b1b  = (const float*)d_in[5];
    const float* W2a  = (const float*)d_in[6];
    const float* b2a  = (const float*)d_in[7];
    const float* W2b  = (const float*)d_in[8];
    const float* b2b  = (const float*)d_in[9];
    const float* Wlin = (const float*)d_in[10];
    const float* blin = (const float*)d_in[11];
    float* out = (float*)d_out;

    const int N = in_sizes[0] / 64;   // 100000
    const int E = in_sizes[1] / 2;    // 1600000
    const int NBUCK = (N + BUCKET_NODES - 1) >> BUCKET_SHIFT;  // 196

    // workspace layout
    char* ws = (char*)d_ws;
    const size_t bufBytes = (size_t)N * 128 * sizeof(float);  // 51.2 MB
    __half2* Zbuf = (__half2*)(ws + 0);          // fp16 z (<=25.6 MB)
    char* B = ws + bufBytes;
    size_t off = 3 * bufBytes;
    int* row_start = (int*)(ws + off); off += ((size_t)(N + 1) * 4 + 15) & ~(size_t)15;
    int* cnt       = (int*)(ws + off); off += ((size_t)N * 4 + 15) & ~(size_t)15;
    int* partials  = (int*)(ws + off); off += 4096;
    int* gcur      = (int*)(ws + off); off += 4096;
    int* edge_src  = (int*)(ws + off); off += (size_t)E * 4;
    __half* h116   = (__half*)(ws + off); off += (size_t)N * 128 * 2;  // 25.6 MB
    // B-buffer interior aliases:
    int* gpk = (int*)B;                              // [0 .. 8MB)
    short* wHi = (short*)(B + (32u << 20));
    __half* x16 = (__half*)(B + (36u << 20));
    short* w1aH = wHi + 0;
    short* w1bH = wHi + 8192;
    short* w2aH = wHi + 24576;
    short* w2bH = wHi + 40960;
    short* wlH  = wHi + 57344;
    (void)cnt; (void)partials;

    const int NB_G = (N + 127) / 128;          // 782 MLP blocks
    const int NB_S = (E + EPB - 1) / EPB;      // 782 scatter blocks
    const int NB_A128 = (N + 3) / 4;           // 25000 (1 node/wave)
    const int NB_A64  = (N + 3) / 4;           // 25000 (1 node/wave)
    const int NB_P = 12500;                    // prep blocks

    // 0. gcur = 0 (stream-ordered, graph-safe)
    hipMemsetAsync(gcur, 0, NBUCK_MAX * sizeof(int), stream);

    // 1. merged prep (weights fp16, x->fp16) + edge scatter
    prep_scatter_kernel<<<NB_S + NB_P, 256, 0, stream>>>(ei, E, gcur, gpk, NBUCK, NB_S,
                                                         W1a, W1b, W2a, W2b, Wlin, wHi,
                                                         x, (__half2*)x16, N * 32, NB_P);

    // 2. CSR: fused base/hist/scan/fill
    bucket_build_kernel<<<NBUCK, 1024, 0, stream>>>(gpk, gcur, row_start, edge_src,
                                                    N, E, NBUCK);

    // 3. conv1: fp16 agg + MFMA MLP
    agg64_fp16<<<NB_A64, 256, 0, stream>>>((const __half2*)x16, row_start, edge_src, Zbuf, N);
    mfma_mlp_A<<<NB_G, 256, 0, stream>>>(Zbuf, w1aH, b1a, w1bH, b1b, h116, N);

    // 4. conv2 + head
    agg128_fp16<<<NB_A128, 256, 0, stream>>>((const __half2*)h116, row_start, edge_src, Zbuf, N);
    mfma_mlp_B<<<NB_G, 256, 0, stream>>>(Zbuf, w2aH, b2a, w2bH, b2b,
                                         wlH, blin, out, N);
}

// Round 12
// 304.764 us; speedup vs baseline: 1.1401x; 1.1401x over previous
//
#include <hip/hip_runtime.h>
#include <hip/hip_fp16.h>

// ---------------------------------------------------------------------------
// GIN (2 GINConv layers + linear head) on MI355X.
// Round 27 (= R26 resubmit after broker timeout): R24's per-m-tile MLP
// restructure REGRESSED (311.6 -> 347.5us): it serialized mt0->mt1 through
// the same LDS region (wave-internal RAW, no overlap) and doubled B-fragment
// loads. Reverted MLPs to the R23 barrier-free form (wave-private P regions,
// B reused across both m-tiles, 2 blk/CU). KEPT from R24: merged
// prep||scatter launch (independent workloads), 0-based gcur + memset,
// 1024-thread fused bucket_build. aggs unchanged: random gather pinned at
// 3.8 TB/s (fabric/L3 wall, confirmed 5 rounds).
// ---------------------------------------------------------------------------

typedef __attribute__((ext_vector_type(8))) short short8;
typedef __attribute__((ext_vector_type(8))) _Float16 half8;
typedef __attribute__((ext_vector_type(4))) float f32x4;
union F8 { unsigned u[4]; uint4 u4; short8 s; half8 h; };

// ---------------- CSR build (bucket-binned; fused build) ----------------

constexpr int BUCKET_SHIFT = 9;
constexpr int BUCKET_NODES = 1 << BUCKET_SHIFT;
constexpr int CAP = 10240;
constexpr int EPB = 2048;
constexpr int NBUCK_MAX = 256;

// merged prep + scatter: blocks [0,nbs) bin edges into gpk (gcur 0-based,
// memset beforehand); blocks [nbs, nbs+npb) convert weights + x -> fp16.
__global__ __launch_bounds__(256) void prep_scatter_kernel(const int* __restrict__ ei, int E,
                                                           int* __restrict__ gcur,
                                                           int* __restrict__ gpk,
                                                           int nbuck, int nbs,
                                                           const float* __restrict__ W1a,
                                                           const float* __restrict__ W1b,
                                                           const float* __restrict__ W2a,
                                                           const float* __restrict__ W2b,
                                                           const float* __restrict__ Wlin,
                                                           short* __restrict__ hi,
                                                           const float* __restrict__ x,
                                                           __half2* __restrict__ x16, int n2,
                                                           int npb) {
    __shared__ int spk[EPB];
    __shared__ unsigned char sbuck[EPB];
    __shared__ int lcnt[NBUCK_MAX];
    __shared__ int lbase[NBUCK_MAX];
    __shared__ int lcur[NBUCK_MAX];
    __shared__ int gbase[NBUCK_MAX];
    __shared__ int stmp[256];

    const int t = threadIdx.x;

    if (blockIdx.x >= nbs) {
        // ---- prep branch ----
        int pb = blockIdx.x - nbs;
        int i = pb * 256 + t;
        if (i < 65536) {
            const float* W;
            int base, K, N;
            if (i < 8192)       { W = W1a;  base = 0;     K = 64;  N = 128; }
            else if (i < 24576) { W = W1b;  base = 8192;  K = 128; N = 128; }
            else if (i < 40960) { W = W2a;  base = 24576; K = 128; N = 128; }
            else if (i < 57344) { W = W2b;  base = 40960; K = 128; N = 128; }
            else                { W = Wlin; base = 57344; K = 128; N = 64;  }
            int rel = i - base;
            int NT = N >> 4;
            int j  = rel & 7;
            int l  = (rel >> 3) & 63;
            int tc = rel >> 9;            // c*NT + nt
            int nt = tc % NT;
            int c  = tc / NT;
            int n  = nt * 16 + (l & 15);
            int k  = c * 32 + ((l >> 4) << 3) + j;
            float v = W[k * N + n];
            hi[i] = (short)__half_as_ushort(__float2half_rn(v));
        }
        for (int k = i; k < n2; k += npb * 256) {
            float2 v = reinterpret_cast<const float2*>(x)[k];
            x16[k] = __floats2half2_rn(v.x, v.y);
        }
        return;
    }

    // ---- scatter branch ----
    const int e0 = blockIdx.x * EPB;
    const int ecnt = min(EPB, E - e0);

    for (int i = t; i < NBUCK_MAX; i += 256) lcnt[i] = 0;
    __syncthreads();

    for (int i = t; i < ecnt; i += 256) {
        int d = ei[E + e0 + i];
        atomicAdd(&lcnt[d >> BUCKET_SHIFT], 1);
    }
    __syncthreads();

    int v = lcnt[t];
    stmp[t] = v;
    __syncthreads();
    #pragma unroll
    for (int off = 1; off < 256; off <<= 1) {
        int add = (t >= off) ? stmp[t - off] : 0;
        __syncthreads();
        stmp[t] += add;
        __syncthreads();
    }
    lbase[t] = stmp[t] - v;
    lcur[t] = stmp[t] - v;
    __syncthreads();

    for (int i = t; i < ecnt; i += 256) {
        int s = ei[e0 + i];
        int d = ei[E + e0 + i];
        int b = d >> BUCKET_SHIFT;
        int p = atomicAdd(&lcur[b], 1);
        spk[p] = ((d & (BUCKET_NODES - 1)) << 17) | s;
        sbuck[p] = (unsigned char)b;
    }
    __syncthreads();

    if (t < nbuck) {
        int c = lcnt[t];
        gbase[t] = (c > 0) ? atomicAdd(&gcur[t], c) : 0;   // 0-based position
    }
    __syncthreads();

    for (int i = t; i < ecnt; i += 256) {
        int b = sbuck[i];
        int gp = gbase[b] + (i - lbase[b]);                 // within-bucket pos
        if (gp < CAP) gpk[(size_t)b * CAP + gp] = spk[i];
    }
}

// fused: per-block bucket-base scan + hist + per-bucket node scan +
// row_start write + fill. One 1024-thread block per bucket. gcur is 0-based.
__global__ __launch_bounds__(1024) void bucket_build_kernel(const int* __restrict__ gpk,
                                                            const int* __restrict__ gcur,
                                                            int* __restrict__ row_start,
                                                            int* __restrict__ edge_src,
                                                            int N, int E, int nbuck) {
    __shared__ int h[BUCKET_NODES];
    __shared__ int s[BUCKET_NODES];
    __shared__ int sb[NBUCK_MAX];
    __shared__ int bbase_sh;
    const int t = threadIdx.x;
    const int b = blockIdx.x;
    const int base = b << BUCKET_SHIFT;

    if (t < NBUCK_MAX) {
        int c = 0;
        if (t < nbuck) c = min(gcur[t], CAP);
        sb[t] = c;
    }
    for (int i = t; i < BUCKET_NODES; i += 1024) h[i] = 0;
    __syncthreads();
    #pragma unroll
    for (int off = 1; off < NBUCK_MAX; off <<= 1) {
        int add = (t >= off && t < NBUCK_MAX) ? sb[t - off] : 0;
        __syncthreads();
        if (t < NBUCK_MAX) sb[t] += add;
        __syncthreads();
    }
    if (t == 0) {
        int cb0 = min(gcur[b], CAP);
        bbase_sh = sb[b] - cb0;   // exclusive base for this bucket
    }

    int cb = min(gcur[b], CAP);
    const int* pp = gpk + (size_t)b * CAP;
    for (int i = t; i < cb; i += 1024) atomicAdd(&h[((unsigned)pp[i]) >> 17], 1);
    __syncthreads();

    int c0 = (t < BUCKET_NODES) ? h[t] : 0;
    if (t < BUCKET_NODES) s[t] = c0;
    __syncthreads();
    #pragma unroll
    for (int off = 1; off < BUCKET_NODES; off <<= 1) {
        int add = (t >= off && t < BUCKET_NODES) ? s[t - off] : 0;
        __syncthreads();
        if (t < BUCKET_NODES) s[t] += add;
        __syncthreads();
    }
    if (t < BUCKET_NODES) {
        int ex = s[t] - c0 + bbase_sh;
        h[t] = ex;                                   // running cursor
        if (base + t < N) row_start[base + t] = ex;
    }
    if (b == 0 && t == 0) row_start[N] = E;
    __syncthreads();

    for (int i = t; i < cb; i += 1024) {
        unsigned pw = (unsigned)pp[i];
        int p = atomicAdd(&h[pw >> 17], 1);
        edge_src[p] = (int)(pw & 0x1FFFFu);
    }
}

// ---------------- aggregation (wide row gathers, R16 form) ----------------

__device__ inline void acc8(float* a, const uint4& v) {
    const __half2* h = reinterpret_cast<const __half2*>(&v);
    #pragma unroll
    for (int j = 0; j < 4; ++j) {
        float2 f = __half22float2(h[j]);
        a[2 * j]     += f.x;
        a[2 * j + 1] += f.y;
    }
}

__device__ inline uint4 pack8(const float* a) {
    uint4 o;
    __half2 h;
    h = __floats2half2_rn(a[0], a[1]); o.x = *reinterpret_cast<unsigned*>(&h);
    h = __floats2half2_rn(a[2], a[3]); o.y = *reinterpret_cast<unsigned*>(&h);
    h = __floats2half2_rn(a[4], a[5]); o.z = *reinterpret_cast<unsigned*>(&h);
    h = __floats2half2_rn(a[6], a[7]); o.w = *reinterpret_cast<unsigned*>(&h);
    return o;
}

// D=128: one node per wave; each 16-lane group fetches a full 256B row as
// dwordx4, so one wave-instruction covers 4 edges (1 KiB in flight).
__global__ __launch_bounds__(256) void agg128_fp16(const __half2* __restrict__ H16,
                                                   const int* __restrict__ row_start,
                                                   const int* __restrict__ edge_src,
                                                   __half2* __restrict__ Z16, int N) {
    int wave = threadIdx.x >> 6, lane = threadIdx.x & 63;
    int node = blockIdx.x * 4 + wave;
    if (node >= N) return;
    const int lg = lane >> 4;      // edge slot 0..3
    const int lo = lane & 15;      // 16B chunk within the row
    const uint4* Hv = reinterpret_cast<const uint4*>(H16);   // 16 uint4 per row
    int beg = row_start[node], end = row_start[node + 1];

    uint4 selfv = Hv[(size_t)node * 16 + lo];   // broadcast across groups

    float a[8];
    #pragma unroll
    for (int j = 0; j < 8; ++j) a[j] = 0.f;
    if (lg == 0) acc8(a, selfv);

    int i = beg;
    for (; i + 16 <= end; i += 16) {
        int s0 = edge_src[i + lg];
        int s1 = edge_src[i + 4 + lg];
        int s2 = edge_src[i + 8 + lg];
        int s3 = edge_src[i + 12 + lg];
        uint4 v0 = Hv[(size_t)s0 * 16 + lo];
        uint4 v1 = Hv[(size_t)s1 * 16 + lo];
        uint4 v2 = Hv[(size_t)s2 * 16 + lo];
        uint4 v3 = Hv[(size_t)s3 * 16 + lo];
        acc8(a, v0); acc8(a, v1); acc8(a, v2); acc8(a, v3);
    }
    if (i + 8 <= end) {
        int s0 = edge_src[i + lg];
        int s1 = edge_src[i + 4 + lg];
        uint4 v0 = Hv[(size_t)s0 * 16 + lo];
        uint4 v1 = Hv[(size_t)s1 * 16 + lo];
        acc8(a, v0); acc8(a, v1);
        i += 8;
    }
    if (i + 4 <= end) {
        int s0 = edge_src[i + lg];
        uint4 v0 = Hv[(size_t)s0 * 16 + lo];
        acc8(a, v0);
        i += 4;
    }
    int rem = end - i;
    if (lg < rem) {
        int s0 = edge_src[i + lg];
        uint4 v0 = Hv[(size_t)s0 * 16 + lo];
        acc8(a, v0);
    }

    // reduce across the 4 lane groups
    #pragma unroll
    for (int j = 0; j < 8; ++j) {
        a[j] += __shfl_xor(a[j], 16);
        a[j] += __shfl_xor(a[j], 32);
    }

    if (lg == 0) {
        reinterpret_cast<uint4*>(Z16)[(size_t)node * 16 + lo] = pack8(a);
    }
}

// D=64: one node per wave; each 8-lane group fetches a full 128B row as
// dwordx4, so one wave-instruction covers 8 edges (1 KiB in flight).
__global__ __launch_bounds__(256) void agg64_fp16(const __half2* __restrict__ H16,
                                                  const int* __restrict__ row_start,
                                                  const int* __restrict__ edge_src,
                                                  __half2* __restrict__ Z16, int N) {
    int wave = threadIdx.x >> 6, lane = threadIdx.x & 63;
    int node = blockIdx.x * 4 + wave;
    if (node >= N) return;
    const int lg = lane >> 3;      // edge slot 0..7
    const int lo = lane & 7;       // 16B chunk within the row
    const uint4* Hv = reinterpret_cast<const uint4*>(H16);   // 8 uint4 per row
    int beg = row_start[node], end = row_start[node + 1];

    uint4 selfv = Hv[(size_t)node * 8 + lo];

    float a[8];
    #pragma unroll
    for (int j = 0; j < 8; ++j) a[j] = 0.f;
    if (lg == 0) acc8(a, selfv);

    int i = beg;
    for (; i + 16 <= end; i += 16) {
        int s0 = edge_src[i + lg];
        int s1 = edge_src[i + 8 + lg];
        uint4 v0 = Hv[(size_t)s0 * 8 + lo];
        uint4 v1 = Hv[(size_t)s1 * 8 + lo];
        acc8(a, v0); acc8(a, v1);
    }
    if (i + 8 <= end) {
        int s0 = edge_src[i + lg];
        uint4 v0 = Hv[(size_t)s0 * 8 + lo];
        acc8(a, v0);
        i += 8;
    }
    int rem = end - i;
    if (lg < rem) {
        int s0 = edge_src[i + lg];
        uint4 v0 = Hv[(size_t)s0 * 8 + lo];
        acc8(a, v0);
    }

    // reduce across the 8 lane groups
    #pragma unroll
    for (int j = 0; j < 8; ++j) {
        a[j] += __shfl_xor(a[j], 8);
        a[j] += __shfl_xor(a[j], 16);
        a[j] += __shfl_xor(a[j], 32);
    }

    if (lg == 0) {
        reinterpret_cast<uint4*>(Z16)[(size_t)node * 8 + lo] = pack8(a);
    }
}

// ---------------- MFMA fused MLP (fp16, direct-A GEMM-1, no barriers) ------
// R23 form: wave-private P regions (T = 2w, 2w+1), B fragments loaded once
// and reused for both m-tiles, both m-tile chains interleaved for ILP.

template <int K, int NT>
__device__ inline void compute_directA(const __half2* __restrict__ z, int M, int m0,
                                       const short* __restrict__ WH,
                                       int w, int lane, f32x4 (*acc)[8]) {
    constexpr int KC = K / 32;
    const short8* bhp = reinterpret_cast<const short8*>(WH) + lane;
    const int q = lane >> 4, ln = lane & 15;
    const uint4* zr[2];
    #pragma unroll
    for (int mt = 0; mt < 2; ++mt) {
        int row = m0 + (w * 2 + mt) * 16 + ln;
        if (row >= M) row = M - 1;
        zr[mt] = reinterpret_cast<const uint4*>(z + (size_t)row * (K / 2));
    }
    for (int c = 0; c < KC; ++c) {
        F8 bh[NT];
        #pragma unroll
        for (int nt = 0; nt < NT; ++nt) bh[nt].s = bhp[(c * NT + nt) * 64];
        #pragma unroll
        for (int mt = 0; mt < 2; ++mt) {
            F8 ah;
            ah.u4 = zr[mt][c * 4 + q];
            #pragma unroll
            for (int nt = 0; nt < NT; ++nt) {
                acc[mt][nt] = __builtin_amdgcn_mfma_f32_16x16x32_f16(ah.h, bh[nt].h, acc[mt][nt], 0, 0, 0);
            }
        }
    }
}

// GEMM-2/3: A from P (wave-private region written by this wave's epilogue).
template <int K, int NT>
__device__ inline void stage_compute(const unsigned* __restrict__ P,
                                     const short* __restrict__ WH,
                                     int w, int lane, f32x4 (*acc)[8]) {
    constexpr int KC = K / 32;
    const short8* bhp = reinterpret_cast<const short8*>(WH) + lane;
    for (int c = 0; c < KC; ++c) {
        F8 bh[NT];
        #pragma unroll
        for (int nt = 0; nt < NT; ++nt) {
            bh[nt].s = bhp[(c * NT + nt) * 64];
        }
        #pragma unroll
        for (int mt = 0; mt < 2; ++mt) {
            const int T = w * 2 + mt;
            const unsigned* Pb = P + ((T * KC + c) * 8) * 66 + lane;
            unsigned d[8];
            #pragma unroll
            for (int j = 0; j < 8; ++j) d[j] = Pb[j * 66];
            F8 ah;
            #pragma unroll
            for (int j = 0; j < 4; ++j) {
                ah.u[j] = __builtin_amdgcn_perm(d[2 * j + 1], d[2 * j], 0x05040100u);
            }
            #pragma unroll
            for (int nt = 0; nt < NT; ++nt) {
                acc[mt][nt] = __builtin_amdgcn_mfma_f32_16x16x32_f16(ah.h, bh[nt].h, acc[mt][nt], 0, 0, 0);
            }
        }
    }
}

__device__ inline void epilogue_tile(const f32x4* acc, const float* __restrict__ bias,
                                     unsigned* __restrict__ Pout, int T, int lane) {
    int q = lane >> 4, ln = lane & 15;
    #pragma unroll
    for (int nt = 0; nt < 8; ++nt) {
        int col = nt * 16 + ln;
        float b = bias[col];
        int c = col >> 5, jj = col & 7, q2 = (col >> 3) & 3;
        int pb = ((T * 4 + c) * 8 + jj) * 66;
        #pragma unroll
        for (int r = 0; r < 4; ++r) {
            float v = fmaxf(acc[nt][r] + b, 0.f);
            Pout[pb + ((q * 4 + r) | (q2 << 4))] =
                (unsigned)__half_as_ushort(__float2half_rn(v));
        }
    }
}

// conv1 MLP: z16[M,64] -> relu(relu(z@Wa+ba)@Wb+bb) = h1 (fp16)
__global__ __launch_bounds__(256, 2) void mfma_mlp_A(const __half2* __restrict__ z16,
                                                     const short* __restrict__ WaH,
                                                     const float* __restrict__ ba,
                                                     const short* __restrict__ WbH,
                                                     const float* __restrict__ bb,
                                                     __half* __restrict__ H16out, int M) {
    __shared__ unsigned P[8 * 4 * 8 * 66];   // 67584 B (wave-private regions)
    const int t = threadIdx.x;
    const int w = t >> 6, lane = t & 63;
    const int m0 = blockIdx.x * 128;
    const int q = lane >> 4, ln = lane & 15;

    f32x4 acc[2][8];
    #pragma unroll
    for (int mt = 0; mt < 2; ++mt)
        #pragma unroll
        for (int i = 0; i < 8; ++i) acc[mt][i] = (f32x4){0.f, 0.f, 0.f, 0.f};
    compute_directA<64, 8>(z16, M, m0, WaH, w, lane, acc);
    epilogue_tile(acc[0], ba, P, w * 2 + 0, lane);
    epilogue_tile(acc[1], ba, P, w * 2 + 1, lane);

    #pragma unroll
    for (int mt = 0; mt < 2; ++mt)
        #pragma unroll
        for (int i = 0; i < 8; ++i) acc[mt][i] = (f32x4){0.f, 0.f, 0.f, 0.f};
    stage_compute<128, 8>(P, WbH, w, lane, acc);

    #pragma unroll
    for (int mt = 0; mt < 2; ++mt) {
        #pragma unroll
        for (int nt = 0; nt < 8; ++nt) {
            int col = nt * 16 + ln;
            float b = bb[col];
            #pragma unroll
            for (int r = 0; r < 4; ++r) {
                int row = m0 + (w * 2 + mt) * 16 + q * 4 + r;
                if (row < M) {
                    float v = fmaxf(acc[mt][nt][r] + b, 0.f);
                    H16out[(size_t)row * 128 + col] = __float2half_rn(v);
                }
            }
        }
    }
}

// conv2 MLP + head
__global__ __launch_bounds__(256, 2) void mfma_mlp_B(const __half2* __restrict__ z16,
                                                     const short* __restrict__ WaH,
                                                     const float* __restrict__ ba,
                                                     const short* __restrict__ WbH,
                                                     const float* __restrict__ bb,
                                                     const short* __restrict__ WlH,
                                                     const float* __restrict__ bl,
                                                     float* __restrict__ Out, int M) {
    __shared__ unsigned P[8 * 4 * 8 * 66];   // 67584 B (wave-private regions)
    const int t = threadIdx.x;
    const int w = t >> 6, lane = t & 63;
    const int m0 = blockIdx.x * 128;
    const int q = lane >> 4, ln = lane & 15;

    f32x4 acc[2][8];
    #pragma unroll
    for (int mt = 0; mt < 2; ++mt)
        #pragma unroll
        for (int i = 0; i < 8; ++i) acc[mt][i] = (f32x4){0.f, 0.f, 0.f, 0.f};
    compute_directA<128, 8>(z16, M, m0, WaH, w, lane, acc);
    epilogue_tile(acc[0], ba, P, w * 2 + 0, lane);
    epilogue_tile(acc[1], ba, P, w * 2 + 1, lane);

    #pragma unroll
    for (int mt = 0; mt < 2; ++mt)
        #pragma unroll
        for (int i = 0; i < 8; ++i) acc[mt][i] = (f32x4){0.f, 0.f, 0.f, 0.f};
    stage_compute<128, 8>(P, WbH, w, lane, acc);
    epilogue_tile(acc[0], bb, P, w * 2 + 0, lane);
    epilogue_tile(acc[1], bb, P, w * 2 + 1, lane);

    #pragma unroll
    for (int mt = 0; mt < 2; ++mt)
        #pragma unroll
        for (int i = 0; i < 8; ++i) acc[mt][i] = (f32x4){0.f, 0.f, 0.f, 0.f};
    stage_compute<128, 4>(P, WlH, w, lane, acc);

    #pragma unroll
    for (int mt = 0; mt < 2; ++mt) {
        #pragma unroll
        for (int nt = 0; nt < 4; ++nt) {
            int col = nt * 16 + ln;
            float b = bl[col];
            #pragma unroll
            for (int r = 0; r < 4; ++r) {
                int row = m0 + (w * 2 + mt) * 16 + q * 4 + r;
                if (row < M) Out[(size_t)row * 64 + col] = acc[mt][nt][r] + b;
            }
        }
    }
}

// ---------------------------------------------------------------------------

extern "C" void kernel_launch(void* const* d_in, const int* in_sizes, int n_in,
                              void* d_out, int out_size, void* d_ws, size_t ws_size,
                              hipStream_t stream) {
    const float* x    = (const float*)d_in[0];
    const int*   ei   = (const int*)d_in[1];
    const float* W1a  = (const float*)d_in[2];
    const float* b1a  = (const float*)d_in[3];
    const float* W1b  = (const float*)d_in[4];
    const float* b1b  = (const float*)d_in[5];
    const float* W2a  = (const float*)d_in[6];
    const float* b2a  = (const float*)d_in[7];
    const float* W2b  = (const float*)d_in[8];
    const float* b2b  = (const float*)d_in[9];
    const float* Wlin = (const float*)d_in[10];
    const float* blin = (const float*)d_in[11];
    float* out = (float*)d_out;

    const int N = in_sizes[0] / 64;   // 100000
    const int E = in_sizes[1] / 2;    // 1600000
    const int NBUCK = (N + BUCKET_NODES - 1) >> BUCKET_SHIFT;  // 196

    // workspace layout
    char* ws = (char*)d_ws;
    const size_t bufBytes = (size_t)N * 128 * sizeof(float);  // 51.2 MB
    __half2* Zbuf = (__half2*)(ws + 0);          // fp16 z (<=25.6 MB)
    char* B = ws + bufBytes;
    size_t off = 3 * bufBytes;
    int* row_start = (int*)(ws + off); off += ((size_t)(N + 1) * 4 + 15) & ~(size_t)15;
    int* cnt       = (int*)(ws + off); off += ((size_t)N * 4 + 15) & ~(size_t)15;
    int* partials  = (int*)(ws + off); off += 4096;
    int* gcur      = (int*)(ws + off); off += 4096;
    int* edge_src  = (int*)(ws + off); off += (size_t)E * 4;
    __half* h116   = (__half*)(ws + off); off += (size_t)N * 128 * 2;  // 25.6 MB
    // B-buffer interior aliases:
    int* gpk = (int*)B;                              // [0 .. 8MB)
    short* wHi = (short*)(B + (32u << 20));
    __half* x16 = (__half*)(B + (36u << 20));
    short* w1aH = wHi + 0;
    short* w1bH = wHi + 8192;
    short* w2aH = wHi + 24576;
    short* w2bH = wHi + 40960;
    short* wlH  = wHi + 57344;
    (void)cnt; (void)partials;

    const int NB_G = (N + 127) / 128;          // 782 MLP blocks
    const int NB_S = (E + EPB - 1) / EPB;      // 782 scatter blocks
    const int NB_A128 = (N + 3) / 4;           // 25000 (1 node/wave)
    const int NB_A64  = (N + 3) / 4;           // 25000 (1 node/wave)
    const int NB_P = 12500;                    // prep blocks

    // 0. gcur = 0 (stream-ordered, graph-safe)
    hipMemsetAsync(gcur, 0, NBUCK_MAX * sizeof(int), stream);

    // 1. merged prep (weights fp16, x->fp16) + edge scatter
    prep_scatter_kernel<<<NB_S + NB_P, 256, 0, stream>>>(ei, E, gcur, gpk, NBUCK, NB_S,
                                                         W1a, W1b, W2a, W2b, Wlin, wHi,
                                                         x, (__half2*)x16, N * 32, NB_P);

    // 2. CSR: fused base/hist/scan/fill
    bucket_build_kernel<<<NBUCK, 1024, 0, stream>>>(gpk, gcur, row_start, edge_src,
                                                    N, E, NBUCK);

    // 3. conv1: fp16 agg + MFMA MLP
    agg64_fp16<<<NB_A64, 256, 0, stream>>>((const __half2*)x16, row_start, edge_src, Zbuf, N);
    mfma_mlp_A<<<NB_G, 256, 0, stream>>>(Zbuf, w1aH, b1a, w1bH, b1b, h116, N);

    // 4. conv2 + head
    agg128_fp16<<<NB_A128, 256, 0, stream>>>((const __half2*)h116, row_start, edge_src, Zbuf, N);
    mfma_mlp_B<<<NB_G, 256, 0, stream>>>(Zbuf, w2aH, b2a, w2bH, b2b,
                                         wlH, blin, out, N);
}